// Round 2
// 245.969 us; speedup vs baseline: 1.0677x; 1.0677x over previous
//
#include <hip/hip_runtime.h>
#include <stdint.h>
#include <stddef.h>

// All-bf16 MFMA pipeline for MHSA: cvt -> gemm_qkv -> flash attn -> gemm_out.
// Attention v7: v6 + double-buffered K/V LDS staging with counted vmcnt(8)
// (prefetch tile t+1 overlaps compute of tile t; no full vmcnt drain before
// compute), s_setprio(1) around MFMA clusters, v_cvt_pk_bf16_f32 P-pack.

typedef __attribute__((ext_vector_type(8))) short short8;     // bf16x8 frag (4 VGPRs)
typedef __attribute__((ext_vector_type(4))) float floatx4;    // 16x16 C/D frag
typedef __attribute__((ext_vector_type(16))) float floatx16;  // 32x32 C/D frag

#define MFMA_BF16(a, b, c) __builtin_amdgcn_mfma_f32_16x16x32_bf16((a), (b), (c), 0, 0, 0)
#define MFMA32_BF16(a, b, c) __builtin_amdgcn_mfma_f32_32x32x16_bf16((a), (b), (c), 0, 0, 0)

__device__ __forceinline__ unsigned short f32_bf16(float f) {
  union { float f; unsigned u; } v; v.f = f;
  unsigned r = v.u + 0x7fffu + ((v.u >> 16) & 1u);   // RNE
  return (unsigned short)(r >> 16);
}

// pack two floats to bf16x2 via HW cvt_pk (RNE): low=a, high=b  (1 VALU op)
__device__ __forceinline__ unsigned cvt_pk_bf16(float a, float b) {
  unsigned r;
  asm("v_cvt_pk_bf16_f32 %0, %1, %2" : "=v"(r) : "v"(a), "v"(b));
  return r;
}

__device__ __forceinline__ float fast_exp2(float x) {
#if __has_builtin(__builtin_amdgcn_exp2f)
  return __builtin_amdgcn_exp2f(x);
#else
  return exp2f(x);
#endif
}

__device__ __forceinline__ void g2l16(const void* g, void* l) {
  __builtin_amdgcn_global_load_lds((const __attribute__((address_space(1))) void*)g,
                                   (__attribute__((address_space(3))) void*)l,
                                   16, 0, 0);
}

// ---------------- conversion kernels ----------------

__global__ __launch_bounds__(256) void cvt_x_k(const float* __restrict__ x,
                                               unsigned short* __restrict__ xb) {
  int i = (blockIdx.x * 256 + threadIdx.x) * 4;
  float4 v = *(const float4*)(x + i);
  ushort4 o;
  o.x = f32_bf16(v.x); o.y = f32_bf16(v.y); o.z = f32_bf16(v.z); o.w = f32_bf16(v.w);
  *(ushort4*)(xb + i) = o;
}

// Merged LDS-tiled transpose-converts:
//  bid <  768: Wqkv[typ*1024 + h*64 + dk][d] = W_typ[h][d][dk]
//  bid >= 768: WOt[n][k] = WO[k][n]
__global__ __launch_bounds__(256) void cvt_w_k(const float* __restrict__ WQ,
                                               const float* __restrict__ WK,
                                               const float* __restrict__ WV,
                                               const float* __restrict__ WO,
                                               unsigned short* __restrict__ Wqkv,
                                               unsigned short* __restrict__ WOt) {
  __shared__ unsigned short tile[64][72];
  const int bid = blockIdx.x;
  const int tid = threadIdx.x;
  if (bid < 768) {
    const int th = bid >> 4;
    const int typ = th >> 4, h = th & 15;
    const float* W = (typ == 0) ? WQ : ((typ == 1) ? WK : WV);
    const float* src = W + ((size_t)h * 1024 + (bid & 15) * 64) * 64;  // [64 d][64 dk]
    #pragma unroll
    for (int it = 0; it < 16; ++it) {
      int f = it * 256 + tid;
      int dk = f & 63, dl = f >> 6;
      tile[dk][dl] = f32_bf16(src[(size_t)dl * 64 + dk]);
    }
    __syncthreads();
    unsigned short* dst = Wqkv + (size_t)(typ * 1024 + h * 64) * 1024 + (bid & 15) * 64;
    #pragma unroll
    for (int it = 0; it < 16; ++it) {
      int f = it * 256 + tid;
      int d = f & 63, dk = f >> 6;
      dst[(size_t)dk * 1024 + d] = tile[dk][d];
    }
  } else {
    const int id2 = bid - 768;
    const int nt = (id2 & 15) * 64, kt = (id2 >> 4) * 64;
    #pragma unroll
    for (int it = 0; it < 16; ++it) {
      int f = it * 256 + tid;
      int n = f & 63, kl = f >> 6;
      tile[n][kl] = f32_bf16(WO[(size_t)(kt + kl) * 1024 + nt + n]);
    }
    __syncthreads();
    #pragma unroll
    for (int it = 0; it < 16; ++it) {
      int f = it * 256 + tid;
      int k = f & 63, nl = f >> 6;
      WOt[(size_t)(nt + nl) * 1024 + kt + k] = tile[nl][k];
    }
  }
}

// ---------------- QKV projection GEMM ----------------
// A[8192][1024] bf16, Bt[3072][1024] bf16 (B^T). 128x128 tile, BK=64,
// 4 waves each 64x64 (4x4 16x16x32 MFMA tiles). Epilogue scatters to
// Q (pre-scaled by 0.125*log2e), K [bh][s][dk], V^T [bh][dk][perm(s)] (bf16)
// where perm swaps bits 2<->3 of the key index (for attn's conflict-free PV).

__global__ __launch_bounds__(256, 2)
void gemm_qkv_k(const unsigned short* __restrict__ A,
                const unsigned short* __restrict__ Bt,
                unsigned short* __restrict__ Qo,
                unsigned short* __restrict__ Ko,
                unsigned short* __restrict__ Vo) {
  __shared__ __align__(16) unsigned short As[8192];
  __shared__ __align__(16) unsigned short Bs[8192];
  const int lane = threadIdx.x & 63;
  const int wave = threadIdx.x >> 6;
  const int quad = lane >> 4;
  const int t = lane & 15;
  const int wm = wave >> 1, wn = wave & 1;
  const int row0 = blockIdx.y * 128;
  const int col0 = blockIdx.x * 128;

  floatx4 acc[4][4];
  #pragma unroll
  for (int i = 0; i < 4; ++i)
    #pragma unroll
    for (int j = 0; j < 4; ++j) acc[i][j] = (floatx4)0.0f;

  for (int k0 = 0; k0 < 1024; k0 += 64) {
    #pragma unroll
    for (int i = 0; i < 4; ++i) {
      int s = (wave * 4 + i) * 64 + lane;       // 16B slot index
      int r = s >> 3, kc = (s & 7) ^ (r & 7);   // swizzle8
      g2l16(A  + (size_t)(row0 + r) * 1024 + k0 + kc * 8, As + (wave * 4 + i) * 512);
      g2l16(Bt + (size_t)(col0 + r) * 1024 + k0 + kc * 8, Bs + (wave * 4 + i) * 512);
    }
    __syncthreads();
    #pragma unroll
    for (int kk = 0; kk < 2; ++kk) {
      short8 af[4], bf[4];
      #pragma unroll
      for (int mt = 0; mt < 4; ++mt) {
        int r = wm * 64 + mt * 16 + t;
        int kc = (kk * 4 + quad) ^ (r & 7);
        af[mt] = *(const short8*)(As + (r * 8 + kc) * 8);
      }
      #pragma unroll
      for (int nt = 0; nt < 4; ++nt) {
        int r = wn * 64 + nt * 16 + t;
        int kc = (kk * 4 + quad) ^ (r & 7);
        bf[nt] = *(const short8*)(Bs + (r * 8 + kc) * 8);
      }
      #pragma unroll
      for (int mt = 0; mt < 4; ++mt)
        #pragma unroll
        for (int nt = 0; nt < 4; ++nt)
          acc[mt][nt] = MFMA_BF16(af[mt], bf[nt], acc[mt][nt]);
    }
    __syncthreads();
  }

  const int typ = col0 >> 10;  // block-uniform: 0=Q 1=K 2=V
  const float qscale = 0.18033688011112042f;  // 0.125 * log2(e) folded into Q
  const int qp = ((quad & 1) << 1) | (quad >> 1);  // swap bits: 0,2,1,3
  #pragma unroll
  for (int mt = 0; mt < 4; ++mt) {
    int grow0 = row0 + wm * 64 + mt * 16 + quad * 4;  // token, + rg
    int b = grow0 >> 11;
    int s = grow0 & 2047;
    #pragma unroll
    for (int nt = 0; nt < 4; ++nt) {
      int gcol = col0 + wn * 64 + nt * 16 + t;
      int rem = gcol & 1023;
      int h = rem >> 6, dk = rem & 63;
      int bhh = b * 16 + h;
      if (typ == 0) {
        #pragma unroll
        for (int rg = 0; rg < 4; ++rg)
          Qo[((size_t)bhh * 2048 + s + rg) * 64 + dk] = f32_bf16(acc[mt][nt][rg] * qscale);
      } else if (typ == 1) {
        #pragma unroll
        for (int rg = 0; rg < 4; ++rg)
          Ko[((size_t)bhh * 2048 + s + rg) * 64 + dk] = f32_bf16(acc[mt][nt][rg]);
      } else {
        ushort4 pv;
        pv.x = f32_bf16(acc[mt][nt][0]);
        pv.y = f32_bf16(acc[mt][nt][1]);
        pv.z = f32_bf16(acc[mt][nt][2]);
        pv.w = f32_bf16(acc[mt][nt][3]);
        int sp = (s & ~15) | (qp << 2);           // key-permuted V^T
        *(ushort4*)(Vo + ((size_t)bhh * 64 + dk) * 2048 + sp) = pv;
      }
    }
  }
}

// ---------------- flash attention v7 ----------------
// Block = 256 q rows of one (b,h); 4 waves x 64 q (two 32-q groups sharing all
// K/V B-frag reads). 128-key tiles, DOUBLE-BUFFERED in LDS (2 x 32KB = 64KB):
// tile t+1's 8 g2l16/thread are issued before computing tile t, then a counted
// s_waitcnt vmcnt(8) + raw s_barrier lets the prefetch stay in flight across
// the barrier (no vmcnt(0) drain in the main loop). Hazard: tile t+1 lands in
// the buffer last read at iteration t-1; the end-of-iteration s_barrier plus
// per-wave lgkm waits (compiler, before MFMA use) retire all reads first.
// S^T C-layout: lane (c32,h32) reg r holds P[key kb*32+(r&3)+8*(r>>2)+4*h32][query c32].
// V key-permuted (bit2<->bit3) -> PV step (kb,st): A-frag = pk[4st..4st+3],
// B-frag = one b128 at granule col kb*4+st*2+h32. Row sums via MFMA ones.
// Grid (bh=64, qtile=8): flat id % 8 == bh % 8 -> per-head XCD L2 affinity.

__global__ __launch_bounds__(256, 2)
void attn_k(const unsigned short* __restrict__ Qg_,  // [bh][2048][64], pre-scaled
            const unsigned short* __restrict__ Kg_,  // [bh][2048][64]
            const unsigned short* __restrict__ Vg_,  // [bh][64][2048] (V^T, key-perm)
            unsigned short* __restrict__ O) {        // [token][h*64+dk]
  __shared__ __align__(16) char smem[65536];  // buf p: K@p*32768 [128k][64d], V@+16384 [64d][128k]
  const int lane = threadIdx.x & 63;
  const int wave = threadIdx.x >> 6;
  const int h32 = lane >> 5;
  const int c32 = lane & 31;
  const int bh = blockIdx.x;
  const int q0 = blockIdx.y * 256;
  const unsigned short* Qg = Qg_ + ((size_t)bh * 2048 + q0) * 64;
  const unsigned short* Kg = Kg_ + (size_t)bh * 2048 * 64;
  const unsigned short* Vg = Vg_ + (size_t)bh * 64 * 2048;

  // Q B-frags straight from global for both query groups:
  // group g covers queries wave*64 + g*32 + c32; B[n=query][k=8*h32+j]
  short8 qf[2][4];
  #pragma unroll
  for (int g = 0; g < 2; ++g) {
    int rq = wave * 64 + g * 32 + c32;
    #pragma unroll
    for (int dc = 0; dc < 4; ++dc)
      qf[g][dc] = *(const short8*)(Qg + (size_t)rq * 64 + dc * 16 + h32 * 8);
  }

  // ones B-frag for MFMA row sums
  union { unsigned u[4]; short8 s8; } onesf;
  #pragma unroll
  for (int i = 0; i < 4; ++i) onesf.u[i] = 0x3F803F80u;

  floatx16 acc[2][2], accs[2];
  #pragma unroll
  for (int g = 0; g < 2; ++g) {
    acc[g][0] = (floatx16)0.0f; acc[g][1] = (floatx16)0.0f; accs[g] = (floatx16)0.0f;
  }

  // stage one 128-key tile (K 16KB + V 16KB) into buffer at byte offset boff:
  // 8 g2l16 per thread. K swz8 (8 granules/row), V^T(perm) swz (16 gran/row).
  auto stage = [&](int s0, int boff) {
    #pragma unroll
    for (int i = 0; i < 4; ++i) {
      int s = (wave * 4 + i) * 64 + lane;          // granule slot 0..1023
      int rk = s >> 3, ck = (s & 7) ^ (rk & 7);
      g2l16(Kg + (size_t)(s0 + rk) * 64 + ck * 8, smem + boff + s * 16);
      int rv = s >> 4, cv = (s & 15) ^ (rv & 7);
      g2l16(Vg + (size_t)rv * 2048 + s0 + cv * 8, smem + boff + 16384 + s * 16);
    }
  };

  stage(0, 0);
  asm volatile("s_waitcnt vmcnt(0)\ns_barrier" ::: "memory");

  for (int it = 0; it < 16; ++it) {
    const int boff = (it & 1) << 15;               // 0 / 32768
    if (it < 15) {
      stage((it + 1) * 128, boff ^ 32768);         // prefetch overlaps this tile's compute
      asm volatile("s_waitcnt vmcnt(8)\ns_barrier" ::: "memory");  // only new 8 in flight
    } else {
      asm volatile("s_waitcnt vmcnt(0)\ns_barrier" ::: "memory");
    }
    const char* kbase = smem + boff;
    const char* vbase = smem + boff + 16384;

    #pragma unroll
    for (int kb = 0; kb < 4; ++kb) {
      // S^T = K * Q^T for 32 keys (kb block), both query groups share kf
      floatx16 sc0 = (floatx16)0.0f, sc1 = (floatx16)0.0f;
      __builtin_amdgcn_s_setprio(1);
      #pragma unroll
      for (int dc = 0; dc < 4; ++dc) {
        int rk = kb * 32 + c32;
        int kc = (dc * 2 + h32) ^ (rk & 7);
        short8 kf = *(const short8*)(kbase + (rk * 8 + kc) * 16);
        sc0 = MFMA32_BF16(kf, qf[0][dc], sc0);
        sc1 = MFMA32_BF16(kf, qf[1][dc], sc1);
      }
      __builtin_amdgcn_s_setprio(0);
      // softmax + pack for both groups (v_cvt_pk_bf16_f32: 1 op / 2 values)
      unsigned pk0[8], pk1[8];
      #pragma unroll
      for (int i = 0; i < 8; ++i) {
        float a0 = fast_exp2(sc0[2 * i]), b0 = fast_exp2(sc0[2 * i + 1]);
        float a1 = fast_exp2(sc1[2 * i]), b1 = fast_exp2(sc1[2 * i + 1]);
        pk0[i] = cvt_pk_bf16(a0, b0);
        pk1[i] = cvt_pk_bf16(a1, b1);
      }
      // O += P*V ; rowsum += P*1  (V key-permuted => single b128 B-frag, shared)
      __builtin_amdgcn_s_setprio(1);
      #pragma unroll
      for (int st = 0; st < 2; ++st) {
        union { unsigned u[4]; short8 s8; } af0, af1;
        #pragma unroll
        for (int i = 0; i < 4; ++i) { af0.u[i] = pk0[4 * st + i]; af1.u[i] = pk1[4 * st + i]; }
        int cc = kb * 4 + st * 2 + h32;
        #pragma unroll
        for (int nb = 0; nb < 2; ++nb) {
          int rv = nb * 32 + c32;
          short8 bv = *(const short8*)(vbase + (rv * 16 + (cc ^ (rv & 7))) * 16);
          acc[0][nb] = MFMA32_BF16(af0.s8, bv, acc[0][nb]);
          acc[1][nb] = MFMA32_BF16(af1.s8, bv, acc[1][nb]);
        }
        accs[0] = MFMA32_BF16(af0.s8, onesf.s8, accs[0]);
        accs[1] = MFMA32_BF16(af1.s8, onesf.s8, accs[1]);
      }
      __builtin_amdgcn_s_setprio(0);
    }
    asm volatile("s_barrier" ::: "memory");        // reads done before next overwrite
  }

  const int b = bh >> 4, h = bh & 15;
  #pragma unroll
  for (int g = 0; g < 2; ++g) {
    #pragma unroll
    for (int gg = 0; gg < 4; ++gg) {
      #pragma unroll
      for (int rr = 0; rr < 4; ++rr) {
        int qrel = rr + 8 * gg + 4 * h32;            // 32x32 C/D row mapping
        float rl = 1.0f / accs[g][4 * gg + rr];      // rowsum of this query
        int token = b * 2048 + q0 + wave * 64 + g * 32 + qrel;
        size_t base = (size_t)token * 1024 + h * 64;
        O[base + c32]      = f32_bf16(acc[g][0][4 * gg + rr] * rl);
        O[base + 32 + c32] = f32_bf16(acc[g][1][4 * gg + rr] * rl);
      }
    }
  }
}

// ---------------- output projection GEMM (fp32 out) ----------------

__global__ __launch_bounds__(256, 2)
void gemm_out_k(const unsigned short* __restrict__ A,    // O concat [8192][1024]
                const unsigned short* __restrict__ Bt,   // WOt [1024][1024]
                float* __restrict__ C) {
  __shared__ __align__(16) unsigned short As[8192];
  __shared__ __align__(16) unsigned short Bs[8192];
  const int lane = threadIdx.x & 63;
  const int wave = threadIdx.x >> 6;
  const int quad = lane >> 4;
  const int t = lane & 15;
  const int wm = wave >> 1, wn = wave & 1;
  const int row0 = blockIdx.y * 128;
  const int col0 = blockIdx.x * 128;

  floatx4 acc[4][4];
  #pragma unroll
  for (int i = 0; i < 4; ++i)
    #pragma unroll
    for (int j = 0; j < 4; ++j) acc[i][j] = (floatx4)0.0f;

  for (int k0 = 0; k0 < 1024; k0 += 64) {
    #pragma unroll
    for (int i = 0; i < 4; ++i) {
      int s = (wave * 4 + i) * 64 + lane;
      int r = s >> 3, kc = (s & 7) ^ (r & 7);
      g2l16(A  + (size_t)(row0 + r) * 1024 + k0 + kc * 8, As + (wave * 4 + i) * 512);
      g2l16(Bt + (size_t)(col0 + r) * 1024 + k0 + kc * 8, Bs + (wave * 4 + i) * 512);
    }
    __syncthreads();
    #pragma unroll
    for (int kk = 0; kk < 2; ++kk) {
      short8 af[4], bf[4];
      #pragma unroll
      for (int mt = 0; mt < 4; ++mt) {
        int r = wm * 64 + mt * 16 + t;
        int kc = (kk * 4 + quad) ^ (r & 7);
        af[mt] = *(const short8*)(As + (r * 8 + kc) * 8);
      }
      #pragma unroll
      for (int nt = 0; nt < 4; ++nt) {
        int r = wn * 64 + nt * 16 + t;
        int kc = (kk * 4 + quad) ^ (r & 7);
        bf[nt] = *(const short8*)(Bs + (r * 8 + kc) * 8);
      }
      #pragma unroll
      for (int mt = 0; mt < 4; ++mt)
        #pragma unroll
        for (int nt = 0; nt < 4; ++nt)
          acc[mt][nt] = MFMA_BF16(af[mt], bf[nt], acc[mt][nt]);
    }
    __syncthreads();
  }

  #pragma unroll
  for (int mt = 0; mt < 4; ++mt) {
    int grow0 = row0 + wm * 64 + mt * 16 + quad * 4;
    #pragma unroll
    for (int nt = 0; nt < 4; ++nt) {
      int gcol = col0 + wn * 64 + nt * 16 + t;
      #pragma unroll
      for (int rg = 0; rg < 4; ++rg)
        C[(size_t)(grow0 + rg) * 1024 + gcol] = acc[mt][nt][rg];
    }
  }
}

// ---------------- launcher ----------------

extern "C" void kernel_launch(void* const* d_in, const int* in_sizes, int n_in,
                              void* d_out, int out_size, void* d_ws, size_t ws_size,
                              hipStream_t stream) {
  const float* x  = (const float*)d_in[0];
  const float* WQ = (const float*)d_in[1];
  const float* WK = (const float*)d_in[2];
  const float* WV = (const float*)d_in[3];
  const float* WO = (const float*)d_in[4];
  char* ws = (char*)d_ws;
  // workspace layout (72 MB total):
  unsigned short* xb   = (unsigned short*)(ws);                              // 16MB; reused as O after gemm_qkv
  unsigned short* Wqkv = (unsigned short*)(ws + (size_t)16 * 1024 * 1024);   // 6MB  [3072][1024]
  unsigned short* WOt  = (unsigned short*)(ws + (size_t)22 * 1024 * 1024);   // 2MB  [1024][1024]
  unsigned short* Qb   = (unsigned short*)(ws + (size_t)24 * 1024 * 1024);   // 16MB [64][2048][64]
  unsigned short* Kb   = (unsigned short*)(ws + (size_t)40 * 1024 * 1024);   // 16MB [64][2048][64]
  unsigned short* Vb   = (unsigned short*)(ws + (size_t)56 * 1024 * 1024);   // 16MB [64][64][2048] (V^T key-perm)
  float* out = (float*)d_out;

  cvt_x_k<<<8192, 256, 0, stream>>>(x, xb);
  cvt_w_k<<<1024, 256, 0, stream>>>(WQ, WK, WV, WO, Wqkv, WOt);
  gemm_qkv_k<<<dim3(24, 64), 256, 0, stream>>>(xb, Wqkv, Qb, Kb, Vb);
  attn_k<<<dim3(64, 8), 256, 0, stream>>>(Qb, Kb, Vb, xb /*O reuse*/);
  gemm_out_k<<<dim3(8, 64), 256, 0, stream>>>(xb, WOt, out);
}